// Round 9
// baseline (161.657 us; speedup 1.0000x reference)
//
#include <hip/hip_runtime.h>
#include <hip/hip_bf16.h>
#include <cmath>

#define BATCH 4
#define TLEN  4096
#define CEMB  1024
#define HEAD  64
#define NROWS (BATCH * TLEN)          // 16384 token rows

typedef __bf16 bf16;
typedef __attribute__((ext_vector_type(8))) __bf16 bf16x8;
typedef __attribute__((ext_vector_type(4))) __bf16 bf16x4;
typedef __attribute__((ext_vector_type(4))) float f32x4;

#define QSCALE 0.1803368801111204f    // (1/sqrt(64)) * log2(e)

static __device__ __forceinline__ f32x4 mfma16(bf16x8 a, bf16x8 b, f32x4 c) {
    return __builtin_amdgcn_mfma_f32_16x16x32_bf16(a, b, c, 0, 0, 0);
}

// async 16B/lane global->LDS DMA.  lds base is WAVE-UNIFORM; lane i's 16 B
// land at base + i*16.  Side-effecting intrinsic -> compiler cannot sink it.
static __device__ __forceinline__ void async_ld16(const void* g, void* l) {
    __builtin_amdgcn_global_load_lds(
        (const __attribute__((address_space(1))) void*)g,
        (__attribute__((address_space(3))) void*)l, 16, 0, 0);
}

// ---------------------------------------------------------------------------
// Kernel 0: pack W -> Wt[n][k] bf16 (n = which*64+h).  QSCALE folded into Wq.
// ---------------------------------------------------------------------------
__global__ __launch_bounds__(256) void pack_w(
    const float* __restrict__ Wq, const float* __restrict__ Wk,
    const float* __restrict__ Wv, bf16* __restrict__ Wt)
{
    const int n = blockIdx.x;                 // 0..191
    const int which = n >> 6, h = n & 63;
    const float* W = which == 0 ? Wq : (which == 1 ? Wk : Wv);
    const float s = which == 0 ? QSCALE : 1.0f;
    for (int k = threadIdx.x; k < CEMB; k += 256)
        Wt[(size_t)n * CEMB + k] = (bf16)(W[(size_t)k * HEAD + h] * s);
}

// ---------------------------------------------------------------------------
// Kernel 1: QKV projection v5 (unchanged from R8).  x staged fp32 via
// global_load_lds DMA, double-buffered, k-chunk 128 -> 8 barriers, 24
// mfma/chunk.  Wave = 32 rows x 3 n-tiles; Wt B-frags from L2-hot global.
// ---------------------------------------------------------------------------
__global__ __launch_bounds__(256, 2) void qkv(
    const float* __restrict__ x, const bf16* __restrict__ Wt,
    const float* __restrict__ bq, const float* __restrict__ bk,
    const float* __restrict__ bv,
    bf16* __restrict__ qb, bf16* __restrict__ kb, bf16* __restrict__ vT)
{
    __shared__ __align__(16) float Xsh[2][2][32][64];   // 32 KB

    const int tid  = threadIdx.x;
    const int lane = tid & 63;
    const int wvid = tid >> 6;            // 0..3 -> n-triple
    const int quad = lane >> 4;
    const int col  = lane & 15;
    const int row0 = blockIdx.x * 32;     // grid 512

    const float* xblk = x + (size_t)row0 * CEMB;
    const bf16* wrow[3];
    #pragma unroll
    for (int j = 0; j < 3; ++j)
        wrow[j] = Wt + (size_t)((wvid * 3 + j) * 16 + col) * CEMB + quad * 8;

    const int sr = lane >> 4;             // row within wave-load 0..3
    const int ss = lane & 15;             // LDS granule slot
    auto stage = [&](int ci, int bufi) {
        #pragma unroll
        for (int h2 = 0; h2 < 2; ++h2)
            #pragma unroll
            for (int j = 0; j < 2; ++j) {
                const int r = wvid * 8 + j * 4 + sr;
                const int c = ss ^ (r & 7);   // global granule (16B = 4 fp32)
                async_ld16(xblk + (size_t)r * CEMB + ci * 128 + h2 * 64 + c * 4,
                           &Xsh[bufi][h2][wvid * 8 + j * 4][0]);
            }
    };

    f32x4 acc[2][3] = {};                 // [row-tile][n-tile]
    const int c7 = col & 7;

    stage(0, 0);
    int buf = 0;
    for (int ci = 0; ci < 8; ++ci) {      // 8 chunks of 128 k
        __syncthreads();                  // implicit vmcnt(0): DMA(ci) visible
        if (ci + 1 < 8) stage(ci + 1, buf ^ 1);   // in flight across compute

        #pragma unroll
        for (int kk = 0; kk < 4; ++kk) {  // 4 x 32-k steps
            const int h  = ci * 4 + kk;
            const int hf = kk >> 1;       // which 64-col half
            const int kl = kk & 1;
            bf16x8 Bv[3];
            #pragma unroll
            for (int j = 0; j < 3; ++j)
                Bv[j] = *(const bf16x8*)(wrow[j] + h * 32);
            #pragma unroll
            for (int rt = 0; rt < 2; ++rt) {
                const int r = rt * 16 + col;
                const int g0 = kl * 8 + quad * 2;
                float4 a0 = *(const float4*)&Xsh[buf][hf][r][(g0 ^ c7) * 4];
                float4 a1 = *(const float4*)&Xsh[buf][hf][r][((g0 + 1) ^ c7) * 4];
                bf16x8 af;
                af[0]=(bf16)a0.x; af[1]=(bf16)a0.y; af[2]=(bf16)a0.z; af[3]=(bf16)a0.w;
                af[4]=(bf16)a1.x; af[5]=(bf16)a1.y; af[6]=(bf16)a1.z; af[7]=(bf16)a1.w;
                #pragma unroll
                for (int j = 0; j < 3; ++j)
                    acc[rt][j] = mfma16(af, Bv[j], acc[rt][j]);
            }
        }
        buf ^= 1;
    }

    const float* bias[3] = {bq, bk, bv};
    #pragma unroll
    for (int j = 0; j < 3; ++j) {
        const int jg = wvid * 3 + j;      // global n-tile 0..11
        const int which = jg >> 2;
        const int h = (jg & 3) * 16 + col;
        float bb = bias[which][h];
        if (which == 0) bb *= QSCALE;
        #pragma unroll
        for (int rt = 0; rt < 2; ++rt) {
            if (which < 2) {
                bf16* dst = which == 0 ? qb : kb;
                #pragma unroll
                for (int r = 0; r < 4; ++r) {
                    const int trow = row0 + rt * 16 + quad * 4 + r;
                    dst[(size_t)trow * HEAD + h] = (bf16)(acc[rt][j][r] + bb);
                }
            } else {                      // v -> vT[b][h][t], 4 contig t
                bf16x4 pv;
                #pragma unroll
                for (int r = 0; r < 4; ++r) pv[r] = (bf16)(acc[rt][j][r] + bb);
                const int trow0 = row0 + rt * 16 + quad * 4;
                const int bb_   = trow0 >> 12;
                const int tt    = trow0 & (TLEN - 1);
                *(bf16x4*)(vT + ((size_t)(bb_ * HEAD + h)) * TLEN + tt) = pv;
            }
        }
    }
}

// ---------------------------------------------------------------------------
// Kernel 2: attention v5.  R8 post-mortem: 64-row waves needed ~200 VGPR
// under a 128-cap -> spills cancelled the gain.  Revert to R7 shape (2
// q-tiles/wave, grid 1024, 3 blocks/CU) + ONE R8 idea kept: K-fragments
// hoisted to registers once per chunk (Psh may-alias writes otherwise force
// a second LDS read per q-tile).  (256,3): ~170 VGPR cap, no spill.
// ---------------------------------------------------------------------------
__global__ __launch_bounds__(256, 3) void attn(
    const bf16* __restrict__ qb, const bf16* __restrict__ kb,
    const bf16* __restrict__ vT,
    bf16* __restrict__ opart, float* __restrict__ lpart,
    float* __restrict__ out, int nsplit, int lg2S)
{
    __shared__ __align__(16) bf16 Ksh[2][64][64];   // 16 KB
    __shared__ __align__(16) bf16 Vsh[2][64][64];   // 16 KB (V^T: [h][s])
    __shared__ __align__(16) bf16 Psh[4][16][64];   // 8 KB per-wave P bounce

    const int tid  = threadIdx.x;
    const int lane = tid & 63;
    const int wvid = tid >> 6;
    const int quad = lane >> 4;
    const int col  = lane & 15;

    // block decode: 32 q-tiles of 128 rows; whole (b,sp) combos per XCD
    int b, sp, qtile;
    {
        const int id = blockIdx.x;
        if (nsplit >= 2) {
            const int cpx = (BATCH << lg2S) >> 3;   // combos per XCD
            const int idx = id >> 3;
            const int combo = (id & 7) * cpx + (idx >> 5);
            qtile = idx & 31;
            b = combo >> lg2S;
            sp = combo & (nsplit - 1);
        } else {
            qtile = id & 31; b = id >> 5; sp = 0;
        }
    }
    const int q0 = qtile * 128 + wvid * 32;
    const size_t rowbase = (size_t)b * TLEN + q0;

    bf16x8 qf[2][2];
    #pragma unroll
    for (int qt = 0; qt < 2; ++qt) {
        const bf16* qp = qb + (rowbase + qt * 16 + col) * HEAD + quad * 8;
        qf[qt][0] = *(const bf16x8*)qp;
        qf[qt][1] = *(const bf16x8*)(qp + 32);
    }
    const bf16* kbB = kb + (size_t)b * TLEN * HEAD;
    const bf16* vTB = vT + (size_t)b * HEAD * TLEN;

    f32x4 o[2][4] = {};
    float lsum[2] = {0.f, 0.f};

    const int slen = TLEN >> lg2S;
    const int sbeg = sp * slen;
    const int nch  = slen / 64;

    const int r8 = lane >> 3;            // 0..7
    const int s8 = lane & 7;
    auto stage = [&](int s0, int bufi) {
        #pragma unroll
        for (int j = 0; j < 2; ++j) {
            const int r = wvid * 16 + j * 8 + r8;
            const int c = s8 ^ (r & 7);  // global granule (16B = 8 bf16)
            async_ld16(kbB + (size_t)(s0 + r) * HEAD + c * 8,
                       &Ksh[bufi][wvid * 16 + j * 8][0]);
            async_ld16(vTB + (size_t)r * TLEN + s0 + c * 8,
                       &Vsh[bufi][wvid * 16 + j * 8][0]);
        }
    };

    stage(sbeg, 0);
    int buf = 0;
    for (int ci = 0; ci < nch; ++ci) {
        __syncthreads();                 // implicit vmcnt(0): DMA(ci) visible
        if (ci + 1 < nch) stage(sbeg + (ci + 1) * 64, buf ^ 1);

        const int c7 = col & 7;
        // K fragments once per chunk, reused across both q-tiles
        bf16x8 kf[4][2];
        #pragma unroll
        for (int t = 0; t < 4; ++t) {
            const int r = t * 16 + col;
            kf[t][0] = *(const bf16x8*)&Ksh[buf][r][(quad ^ c7) * 8];
            kf[t][1] = *(const bf16x8*)&Ksh[buf][r][((4 + quad) ^ c7) * 8];
        }
        bf16x8 pb[2][2];
        bf16* Pb = &Psh[wvid][col][0];
        #pragma unroll
        for (int qt = 0; qt < 2; ++qt) {
            f32x4 st[4];
            #pragma unroll
            for (int t = 0; t < 4; ++t) {
                f32x4 z = {0.f, 0.f, 0.f, 0.f};
                z = mfma16(kf[t][0], qf[qt][0], z);
                z = mfma16(kf[t][1], qf[qt][1], z);
                st[t] = z;
            }
            #pragma unroll
            for (int t = 0; t < 4; ++t) {
                float p0 = __builtin_amdgcn_exp2f(st[t][0]);
                float p1 = __builtin_amdgcn_exp2f(st[t][1]);
                float p2 = __builtin_amdgcn_exp2f(st[t][2]);
                float p3 = __builtin_amdgcn_exp2f(st[t][3]);
                lsum[qt] += (p0 + p1) + (p2 + p3);
                bf16x4 pv = {(bf16)p0, (bf16)p1, (bf16)p2, (bf16)p3};
                const int g = ((2 * t + (quad >> 1)) ^ c7) * 8 + (quad & 1) * 4;
                *(bf16x4*)(Pb + g) = pv;
            }
            pb[qt][0] = *(const bf16x8*)(Pb + ((quad ^ c7) * 8));
            pb[qt][1] = *(const bf16x8*)(Pb + (((4 + quad) ^ c7) * 8));
        }
        #pragma unroll
        for (int ht = 0; ht < 4; ++ht) {
            const int r = ht * 16 + col;
            bf16x8 v0 = *(const bf16x8*)&Vsh[buf][r][(quad ^ c7) * 8];
            bf16x8 v1 = *(const bf16x8*)&Vsh[buf][r][((4 + quad) ^ c7) * 8];
            o[0][ht] = mfma16(v0, pb[0][0], o[0][ht]);
            o[0][ht] = mfma16(v1, pb[0][1], o[0][ht]);
            o[1][ht] = mfma16(v0, pb[1][0], o[1][ht]);
            o[1][ht] = mfma16(v1, pb[1][1], o[1][ht]);
        }
        buf ^= 1;
    }

    #pragma unroll
    for (int qt = 0; qt < 2; ++qt) {
        lsum[qt] += __shfl_xor(lsum[qt], 16, 64);
        lsum[qt] += __shfl_xor(lsum[qt], 32, 64);
    }

    #pragma unroll
    for (int qt = 0; qt < 2; ++qt) {
        const size_t grow = rowbase + qt * 16 + col;
        if (nsplit == 1) {
            const float inv = 1.f / lsum[qt];
            float* ob = out + grow * HEAD;
            #pragma unroll
            for (int ht = 0; ht < 4; ++ht) {
                f32x4 r = o[qt][ht] * inv;
                *(f32x4*)(ob + ht * 16 + quad * 4) = r;
            }
        } else if (sp == 0) {             // split-0 partial lives in out (fp32)
            float* ob = out + grow * HEAD;
            #pragma unroll
            for (int ht = 0; ht < 4; ++ht)
                *(f32x4*)(ob + ht * 16 + quad * 4) = o[qt][ht];
            if (quad == 0) lpart[grow] = lsum[qt];
        } else {                          // splits 1.. -> bf16 opart
            bf16* ob = opart + ((size_t)(sp - 1) * NROWS + grow) * HEAD;
            #pragma unroll
            for (int ht = 0; ht < 4; ++ht) {
                bf16x4 r;
                #pragma unroll
                for (int rr = 0; rr < 4; ++rr) r[rr] = (bf16)o[qt][ht][rr];
                *(bf16x4*)(ob + ht * 16 + quad * 4) = r;
            }
            if (quad == 0) lpart[(size_t)sp * NROWS + grow] = lsum[qt];
        }
    }
}

// ---------------------------------------------------------------------------
// Kernel 3: combine.  Fixed-max partials share one scale -> plain sums.
// ---------------------------------------------------------------------------
__global__ __launch_bounds__(256) void combine(
    const bf16* __restrict__ opart, const float* __restrict__ lpart,
    float* __restrict__ out, int nsplit)
{
    const int gid = blockIdx.x * 256 + threadIdx.x;
    const int row = gid >> 4;
    const int h4  = (gid & 15) * 4;

    float L = 0.f;
    for (int s = 0; s < nsplit; ++s) L += lpart[(size_t)s * NROWS + row];
    f32x4 O = *(const f32x4*)(out + (size_t)row * HEAD + h4);
    for (int s = 1; s < nsplit; ++s) {
        bf16x4 v = *(const bf16x4*)(opart + ((size_t)(s - 1) * NROWS + row) * HEAD + h4);
        O[0] += (float)v[0]; O[1] += (float)v[1];
        O[2] += (float)v[2]; O[3] += (float)v[3];
    }
    f32x4 r = O * (1.f / L);
    *(f32x4*)(out + (size_t)row * HEAD + h4) = r;
}

// ---------------------------------------------------------------------------
extern "C" void kernel_launch(void* const* d_in, const int* in_sizes, int n_in,
                              void* d_out, int out_size, void* d_ws, size_t ws_size,
                              hipStream_t stream) {
    const float* x  = (const float*)d_in[0];
    const float* Wq = (const float*)d_in[1];
    const float* bq = (const float*)d_in[2];
    const float* Wk = (const float*)d_in[3];
    const float* bk = (const float*)d_in[4];
    const float* Wv = (const float*)d_in[5];
    const float* bv = (const float*)d_in[6];
    float* out = (float*)d_out;

    const size_t n_tok = (size_t)NROWS * HEAD;          // 1,048,576
    char* ws = (char*)d_ws;
    bf16* qb = (bf16*)ws;
    bf16* kb = qb + n_tok;
    bf16* vT = kb + n_tok;
    bf16* Wt = vT + n_tok;
    const size_t base = 3 * n_tok * sizeof(bf16) + 192 * CEMB * sizeof(bf16);

    auto need = [&](int S) {
        return base + (size_t)(S - 1) * n_tok * sizeof(bf16)
                    + (size_t)S * NROWS * sizeof(float);
    };
    int S = 1, lg2S = 0;
    if      (ws_size >= need(8)) { S = 8; lg2S = 3; }
    else if (ws_size >= need(4)) { S = 4; lg2S = 2; }
    else if (ws_size >= need(2)) { S = 2; lg2S = 1; }
    bf16*  opart = Wt + 192 * CEMB;
    float* lpart = (float*)(opart + (size_t)(S - 1) * n_tok);

    pack_w<<<dim3(192), dim3(256), 0, stream>>>(Wq, Wk, Wv, Wt);
    qkv<<<dim3(512), dim3(256), 0, stream>>>(x, Wt, bq, bk, bv, qb, kb, vT);
    attn<<<dim3(32 * BATCH * S), dim3(256), 0, stream>>>(
        qb, kb, vT, opart, lpart, out, S, lg2S);
    if (S > 1)
        combine<<<dim3((NROWS * 16) / 256), dim3(256), 0, stream>>>(
            opart, lpart, out, S);
}